// Round 15
// baseline (211.565 us; speedup 1.0000x reference)
//
#include <hip/hip_runtime.h>
#include <hip/hip_bf16.h>
#include <math.h>

#define BATCH 2048
#define INDIM 512
#define HID   256
#define NRIM  16
#define VAL   400
#define ONUM  8
#define CH    4
#define CK    32
#define CV    256
#define KACT  8
#define K2P   704   // GRU K padded to multiple of 64 (672 -> 704)

typedef __hip_bfloat16 hbf;
typedef __attribute__((ext_vector_type(8))) __bf16 bf16x8;
typedef __attribute__((ext_vector_type(4))) float f32x4;

__device__ __forceinline__ float fsig(float x) {
    x = fminf(fmaxf(x, -30.0f), 30.0f);
    return 1.0f / (1.0f + __expf(-x));
}
__device__ __forceinline__ float ftanh_(float x) {
    x = fminf(fmaxf(x, -15.0f), 15.0f);
    float e = __expf(2.0f * x);
    return (e - 1.0f) / (e + 1.0f);
}

__device__ __forceinline__ unsigned packbf(float a, float b) {
    hbf ha = __float2bfloat16(a), hb = __float2bfloat16(b);
    unsigned short ua, ub;
    __builtin_memcpy(&ua, &ha, 2);
    __builtin_memcpy(&ub, &hb, 2);
    return ((unsigned)ub << 16) | ua;
}

#define GLL(g, l) __builtin_amdgcn_global_load_lds(                                   \
    (const __attribute__((address_space(1))) void*)(g),                               \
    (__attribute__((address_space(3))) void*)(l), 16, 0, 0)

// ------- transpose+convert (vectorized): dst[n][coff+cmap(c)][koff+k] = src[n][k][c]
__device__ __forceinline__ void t_conv_body(
    const float* __restrict__ src, hbf* __restrict__ dst,
    int K, int C, long s_ns, long d_ns, int dstride,
    int koff, int coff, int cmode, int bx, int by, int bz, float* tileS)
{
    const int c0 = bx * 32, k0 = by * 32;
    const int t = threadIdx.x;
    float (*tile)[33] = (float(*)[33])tileS;
    const float* s = src + (size_t)bz * s_ns;

    {
        const int kr = t >> 3, cg = t & 7;
        const int k = k0 + kr, c = c0 + cg * 4;
        float4 v;
        if (k < K && c + 3 < C) {
            v = *(const float4*)(s + (size_t)k * C + c);
        } else {
            v.x = (k < K && c + 0 < C) ? s[(size_t)k * C + c + 0] : 0.0f;
            v.y = (k < K && c + 1 < C) ? s[(size_t)k * C + c + 1] : 0.0f;
            v.z = (k < K && c + 2 < C) ? s[(size_t)k * C + c + 2] : 0.0f;
            v.w = (k < K && c + 3 < C) ? s[(size_t)k * C + c + 3] : 0.0f;
        }
        tile[kr][cg * 4 + 0] = v.x;
        tile[kr][cg * 4 + 1] = v.y;
        tile[kr][cg * 4 + 2] = v.z;
        tile[kr][cg * 4 + 3] = v.w;
    }
    __syncthreads();
    {
        const int cr = t >> 3, kg = t & 7;
        const int c = c0 + cr;
        if (c < C) {
            const int cc = coff + (cmode ? (c < 512 ? c : c + 256) : c);
            hbf* drow = dst + (size_t)bz * d_ns + (size_t)cc * dstride + koff + k0 + kg * 4;
            float v0 = tile[kg * 4 + 0][cr];
            float v1 = tile[kg * 4 + 1][cr];
            float v2 = tile[kg * 4 + 2][cr];
            float v3 = tile[kg * 4 + 3][cr];
            *(uint2*)drow = make_uint2(packbf(v0, v1), packbf(v2, v3));
        }
    }
}

// ---------------- mega_prep: all weight transposes + targeted zeros + k1s + k_xb ---
__global__ __launch_bounds__(256)
void mega_prep(const float* __restrict__ h2h_w, const float* __restrict__ x2h_w,
               const float* __restrict__ q_w, const float* __restrict__ k_w,
               const float* __restrict__ v_w, const float* __restrict__ out_w,
               const float* __restrict__ value_w, const float* __restrict__ option,
               const float* __restrict__ p_w, const float* __restrict__ p_b,
               const float* __restrict__ x,
               hbf* __restrict__ W2, hbf* __restrict__ Wqkv, hbf* __restrict__ Wout,
               hbf* __restrict__ Wv, float* __restrict__ p0g, float* __restrict__ maskg,
               hbf* __restrict__ xB)
{
    __shared__ float tileS[32 * 33];
    const int id = blockIdx.x;
    const int t  = threadIdx.x;

    if (id < 3072) {
        int l = id, bz = l / 192, rem = l % 192;
        t_conv_body(h2h_w, W2, 256, 768, 196608L, 720896L, K2P, 0, 0, 1,
                    rem % 24, rem / 24, bz, tileS);
    } else if (id < 8064) {
        int l = id - 3072, bz = l / 312, rem = l % 312;
        t_conv_body(x2h_w, W2, 400, 768, 307200L, 720896L, K2P, 256, 0, 0,
                    rem % 24, rem / 24, bz, tileS);
    } else if (id < 8576) {
        int l = id - 8064, bz = l / 32, rem = l % 32;
        t_conv_body(q_w, Wqkv, 256, 128, 32768L, 327680L, 256, 0, 0, 0,
                    rem % 4, rem / 4, bz, tileS);
    } else if (id < 9088) {
        int l = id - 8576, bz = l / 32, rem = l % 32;
        t_conv_body(k_w, Wqkv, 256, 128, 32768L, 327680L, 256, 0, 128, 0,
                    rem % 4, rem / 4, bz, tileS);
    } else if (id < 13184) {
        int l = id - 9088, bz = l / 256, rem = l % 256;
        t_conv_body(v_w, Wqkv, 256, 1024, 262144L, 327680L, 256, 0, 256, 0,
                    rem % 32, rem / 32, bz, tileS);
    } else if (id < 17280) {
        int l = id - 13184, bz = l / 256, rem = l % 256;
        t_conv_body(out_w, Wout, 1024, 256, 262144L, 262144L, 1024, 0, 0, 0,
                    rem % 8, rem / 8, bz, tileS);
    } else if (id < 17488) {
        int l = id - 17280;
        t_conv_body(value_w, Wv, 512, 400, 0L, 0L, 512, 0, 0, 0,
                    l % 13, l / 13, 0, tileS);
    } else if (id < 18672) {
        int l = id - 17488, n = l / 74, idx = (l % 74) * 256 + t;
        uint4 z; z.x = 0; z.y = 0; z.z = 0; z.w = 0;
        uint4* base = (uint4*)(W2 + (size_t)n * 720896);
        if (idx < 14336) {
            int c = 768 + idx / 56, u = 32 + idx % 56;
            base[(size_t)c * 88 + u] = z;
        } else {
            int i2 = idx - 14336;
            int c = i2 / 6, u = 82 + i2 % 6;
            base[(size_t)c * 88 + u] = z;
        }
    } else if (id < 18700) {
        int idx = (id - 18672) * 256 + t;
        int c = 400 + idx / 64, u = idx % 64;
        uint4 z; z.x = 0; z.y = 0; z.z = 0; z.w = 0;
        ((uint4*)Wv)[(size_t)c * 64 + u] = z;
    } else if (id < 19212) {
        int l = id - 18700, n = l / 32, idx = (l % 32) * 256 + t;
        int c = 512 + idx / 32, u = idx % 32;
        uint4 z; z.x = 0; z.y = 0; z.z = 0; z.w = 0;
        ((uint4*)(W2 + (size_t)n * 720896))[(size_t)c * 88 + u] = z;
    } else if (id < 19340) {
        const int bb = t >> 4, n = t & 15;
        const int b  = (id - 19212) * 16 + bb;
        float (*sc)[17] = (float(*)[17])tileS;
        float s0 = p_b[n], s1 = 0.0f;
        #pragma unroll
        for (int o = 0; o < ONUM; ++o) {
            s0 = fmaf(option[(b * 2 + 0) * ONUM + o], p_w[o * NRIM + n], s0);
            s1 = fmaf(option[(b * 2 + 1) * ONUM + o], p_w[o * NRIM + n], s1);
        }
        sc[bb][n] = s0;
        __syncthreads();
        int rank = 0;
        #pragma unroll
        for (int m = 0; m < NRIM; ++m) {
            float sm = sc[bb][m];
            if (sm > s0 || (sm == s0 && m < n)) rank++;
        }
        float mk = (rank < KACT) ? 1.0f : 0.0f;
        float mx = fmaxf(s0, s1);
        float e0 = __expf(s0 - mx), e1 = __expf(s1 - mx);
        p0g[b * NRIM + n]   = e0 / (e0 + e1);
        maskg[b * NRIM + n] = mk;
    } else {
        int i = (id - 19340) * 256 + t;
        float4 v = ((const float4*)x)[i];
        unsigned lo = packbf(v.x, v.y), hi = packbf(v.z, v.w);
        *(uint2*)(xB + (size_t)i * 4) = make_uint2(lo, hi);
    }
}

// ---------------- k_compact: per-n deterministic row compaction (no atomics) -------
// rowlist[n] = active batches ascending, then inactive batches ascending; rowcnt[n].
__global__ __launch_bounds__(256)
void k_compact(const float* __restrict__ maskg, int* __restrict__ rowcnt,
               int* __restrict__ rowlist)
{
    const int n = blockIdx.x;
    const int t = threadIdx.x;
    __shared__ int scan[256];
    __shared__ int totalA;
    int act[8];
    int cnt = 0;
    #pragma unroll
    for (int i = 0; i < 8; ++i) {
        int b = t * 8 + i;
        act[i] = (maskg[b * NRIM + n] > 0.5f) ? 1 : 0;
        cnt += act[i];
    }
    scan[t] = cnt;
    __syncthreads();
    for (int off = 1; off < 256; off <<= 1) {
        int v = (t >= off) ? scan[t - off] : 0;
        __syncthreads();
        scan[t] += v;
        __syncthreads();
    }
    if (t == 255) { totalA = scan[255]; rowcnt[n] = scan[255]; }
    __syncthreads();
    int aoff = scan[t] - cnt;                 // exclusive active prefix
    int ioff = totalA + (t * 8 - (scan[t] - cnt));  // inactive base
    int* dst = rowlist + n * 2048;
    #pragma unroll
    for (int i = 0; i < 8; ++i) {
        int b = t * 8 + i;
        if (act[i]) dst[aoff++] = b;
        else        dst[ioff++] = b;
    }
}

// ---------------- K1b: A2 assembly, flat-parallel ----------------------------------
__global__ __launch_bounds__(256)
void k1b_a2(const float* __restrict__ hs, const float* __restrict__ vl0,
            const float* __restrict__ p0g, const float* __restrict__ maskg,
            const float* __restrict__ value_b, hbf* __restrict__ A2)
{
    const int b = blockIdx.x;
    const int t = threadIdx.x;
    __shared__ float vS[VAL], bS[VAL];
    __shared__ float p0S[16], mkS[16];
    if (t < 100) {
        ((float4*)vS)[t] = ((const float4*)(vl0 + (size_t)b * 512))[t];
        ((float4*)bS)[t] = ((const float4*)value_b)[t];
    }
    if (t >= 224 && t < 240) p0S[t - 224] = p0g[b * NRIM + (t - 224)];
    if (t >= 240)            mkS[t - 240] = maskg[b * NRIM + (t - 240)];
    __syncthreads();

    const size_t base = (size_t)b * NRIM;

    #pragma unroll
    for (int it = 0; it < 4; ++it) {
        int idx = it * 256 + t;
        int n = idx >> 6, j = idx & 63;
        float4 hv = ((const float4*)(hs + (base + n) * HID))[j];
        uint2 o = make_uint2(packbf(hv.x, hv.y), packbf(hv.z, hv.w));
        *(uint2*)(A2 + (base + n) * K2P + j * 4) = o;
    }

    for (int idx = t; idx < 1600; idx += 256) {
        int n = idx / 100, j = idx - n * 100;
        float p0 = p0S[n], mk = mkS[n];
        float4 v  = ((const float4*)vS)[j];
        float4 bb = ((const float4*)bS)[j];
        float a0 = mk * (p0 * v.x + (1.0f - p0) * bb.x);
        float a1 = mk * (p0 * v.y + (1.0f - p0) * bb.y);
        float a2 = mk * (p0 * v.z + (1.0f - p0) * bb.z);
        float a3 = mk * (p0 * v.w + (1.0f - p0) * bb.w);
        uint2 o = make_uint2(packbf(a0, a1), packbf(a2, a3));
        *(uint2*)(A2 + (base + n) * K2P + 256 + j * 4) = o;
    }

    if (t < 96) {
        int n = t / 6, j = t - n * 6;
        uint4 z; z.x = 0; z.y = 0; z.z = 0; z.w = 0;
        *(uint4*)(A2 + (base + n) * K2P + 656 + j * 8) = z;
    }
}

// ------ MFMA GEMM core: BK=64, swizzled LDS, loop-carried pointers -----------------
__device__ __forceinline__ void gemm_core64(const hbf* __restrict__ A, long lda,
                                            const hbf* __restrict__ B, long ldb,
                                            int K, short* As, short* Bs, f32x4 acc[4][4])
{
    const int t = threadIdx.x;
    const int w = t >> 6, lane = t & 63;
    const int l15 = lane & 15, l4 = lane >> 4;
    const int rl = lane >> 3;
    const int gu = (lane & 7) ^ rl;
    const int l7 = l15 & 7;

    const hbf* pa[4];
    const hbf* pb[4];
    #pragma unroll
    for (int q = 0; q < 4; ++q) {
        int row = q * 32 + w * 8 + rl;
        pa[q] = A + (size_t)row * lda + gu * 8;
        pb[q] = B + (size_t)row * ldb + gu * 8;
    }

    for (int kk = 0; kk < K; kk += 64) {
        __syncthreads();
        #pragma unroll
        for (int q = 0; q < 4; ++q) {
            GLL(pa[q], As + (q * 32 + w * 8) * 64);
            GLL(pb[q], Bs + (q * 32 + w * 8) * 64);
            pa[q] += 64; pb[q] += 64;
        }
        __syncthreads();

        const int wr = w >> 1, wc = w & 1;
        #pragma unroll
        for (int ks = 0; ks < 2; ++ks) {
            const int p = (ks * 4 + l4) ^ l7;
            bf16x8 af[4], bfr[4];
            #pragma unroll
            for (int m = 0; m < 4; ++m)
                af[m] = *(const bf16x8*)(As + (wr * 64 + m * 16 + l15) * 64 + p * 8);
            #pragma unroll
            for (int nb = 0; nb < 4; ++nb)
                bfr[nb] = *(const bf16x8*)(Bs + (wc * 64 + nb * 16 + l15) * 64 + p * 8);
            #pragma unroll
            for (int m = 0; m < 4; ++m)
                #pragma unroll
                for (int nb = 0; nb < 4; ++nb)
                    acc[m][nb] = __builtin_amdgcn_mfma_f32_16x16x32_bf16(af[m], bfr[nb], acc[m][nb], 0, 0, 0);
        }
    }
}

// ---------------- K1v GEMM: vl0[2048][512] = xB @ Wv^T + value_b -------------------
__global__ __launch_bounds__(256)
void k1v(const hbf* __restrict__ xB, const hbf* __restrict__ Wv,
         const float* __restrict__ value_b, float* __restrict__ vl0)
{
    __shared__ __align__(16) short As[128 * 64];
    __shared__ __align__(16) short Bs[128 * 64];
    const int m0 = (blockIdx.x >> 2) * 128;
    const int c0 = (blockIdx.x & 3) * 128;

    const hbf* A = xB + (size_t)m0 * INDIM;
    const hbf* B = Wv + (size_t)c0 * INDIM;

    f32x4 acc[4][4];
    f32x4 zz = {0.0f, 0.0f, 0.0f, 0.0f};
    #pragma unroll
    for (int m = 0; m < 4; ++m)
        #pragma unroll
        for (int nb = 0; nb < 4; ++nb) acc[m][nb] = zz;

    gemm_core64(A, INDIM, B, INDIM, INDIM, As, Bs, acc);

    const int t = threadIdx.x;
    const int w = t >> 6, lane = t & 63, l15 = lane & 15, l4 = lane >> 4;
    const int wr = w >> 1, wc = w & 1;
    #pragma unroll
    for (int nb = 0; nb < 4; ++nb) {
        int col = c0 + wc * 64 + nb * 16 + l15;
        float bias = (col < VAL) ? value_b[col] : 0.0f;
        #pragma unroll
        for (int m = 0; m < 4; ++m)
            #pragma unroll
            for (int j = 0; j < 4; ++j) {
                int row = m0 + wr * 64 + m * 16 + l4 * 4 + j;
                vl0[(size_t)row * 512 + col] = acc[m][nb][j] + bias;
            }
    }
}

// ------ K2 GEMM + fused GRU, gate-aware K-skip + compacted-row phase-2 skip --------
__global__ __launch_bounds__(256)
void k2g(const hbf* __restrict__ A2, const hbf* __restrict__ W2,
         const int* __restrict__ rowcnt, const int* __restrict__ rowlist,
         hbf* __restrict__ hyB)
{
    __shared__ __align__(16) short As[128 * 64];
    __shared__ __align__(16) short Bs[128 * 64];
    const int id = blockIdx.x;
    const int xcd = id & 7, idx = id >> 3;
    const int n  = xcd + ((idx >> 7) << 3);
    const int rem = idx & 127;
    const int m0 = (rem >> 3) * 128;       // compacted batch-tile base
    const int c0 = rem & 7;                // hidden-col strip [0,8)

    const int* rl_n = rowlist + n * 2048;
    const int cntA  = rowcnt[n];
    const bool skip2 = (m0 >= cntA);       // tile fully inactive -> x2h part is all-zero

    const hbf* Bb = W2 + (size_t)n * (1024 * K2P);

    const int t = threadIdx.x;
    const int w = t >> 6, lane = t & 63;
    const int l15 = lane & 15, l4 = lane >> 4;
    const int rl = lane >> 3;
    const int gu = (lane & 7) ^ rl;
    const int l7 = l15 & 7;
    const int wr = w >> 1, wc = w & 1;

    f32x4 acc[4][4];
    f32x4 zz = {0.0f, 0.0f, 0.0f, 0.0f};
    #pragma unroll
    for (int m = 0; m < 4; ++m)
        #pragma unroll
        for (int nb = 0; nb < 4; ++nb) acc[m][nb] = zz;

    const hbf* pa[4];
    const hbf* pb[4];
    int gq[4];
    #pragma unroll
    for (int q = 0; q < 4; ++q) {
        int row = q * 32 + w * 8 + rl;
        int rb  = rl_n[m0 + row];          // gathered batch index
        int wrow = ((row >> 4) & 3) * 256 + c0 * 32 + ((row >> 6) << 4) + (row & 15);
        pa[q] = A2 + ((size_t)rb * NRIM + n) * K2P + gu * 8;
        pb[q] = Bb + (size_t)wrow * K2P + gu * 8;
        gq[q] = (2 * q + (w >> 1)) & 3;    // wave-uniform gate of this staging group
    }

    // ---- phase 1: K [0,256), gates {0,1,3} ----
    for (int kk = 0; kk < 256; kk += 64) {
        __syncthreads();
        #pragma unroll
        for (int q = 0; q < 4; ++q) {
            GLL(pa[q], As + (q * 32 + w * 8) * 64);
            if (gq[q] != 2) GLL(pb[q], Bs + (q * 32 + w * 8) * 64);
            pa[q] += 64; pb[q] += 64;
        }
        __syncthreads();
        #pragma unroll
        for (int ks = 0; ks < 2; ++ks) {
            const int p = (ks * 4 + l4) ^ l7;
            bf16x8 af[4];
            #pragma unroll
            for (int m = 0; m < 4; ++m)
                af[m] = *(const bf16x8*)(As + (wr * 64 + m * 16 + l15) * 64 + p * 8);
            bf16x8 b0 = *(const bf16x8*)(Bs + (wc * 64 + 0 * 16 + l15) * 64 + p * 8);
            bf16x8 b1 = *(const bf16x8*)(Bs + (wc * 64 + 1 * 16 + l15) * 64 + p * 8);
            bf16x8 b3 = *(const bf16x8*)(Bs + (wc * 64 + 3 * 16 + l15) * 64 + p * 8);
            #pragma unroll
            for (int m = 0; m < 4; ++m) {
                acc[m][0] = __builtin_amdgcn_mfma_f32_16x16x32_bf16(af[m], b0, acc[m][0], 0, 0, 0);
                acc[m][1] = __builtin_amdgcn_mfma_f32_16x16x32_bf16(af[m], b1, acc[m][1], 0, 0, 0);
                acc[m][3] = __builtin_amdgcn_mfma_f32_16x16x32_bf16(af[m], b3, acc[m][3], 0, 0, 0);
            }
        }
    }

    // ---- phase 2: K [256,704), gates {0,1,2}; skipped if tile fully inactive ----
    if (!skip2) {
        for (int kk = 256; kk < K2P; kk += 64) {
            __syncthreads();
            #pragma unroll
            for (int q = 0; q < 4; ++q) {
                GLL(pa[q], As + (q * 32 + w * 8) * 64);
                if (gq[q] != 3) GLL(pb[q], Bs + (q * 32 + w * 8) * 64);
                pa[q] += 64; pb[q] += 64;
            }
            __syncthreads();
            #pragma unroll
            for (int ks = 0; ks < 2; ++ks) {
                const int p = (ks * 4 + l4) ^ l7;
                bf16x8 af[4];
                #pragma unroll
                for (int m = 0; m < 4; ++m)
                    af[m] = *(const bf16x8*)(As + (wr * 64 + m * 16 + l15) * 64 + p * 8);
                bf16x8 b0 = *(const bf16x8*)(Bs + (wc * 64 + 0 * 16 + l15) * 64 + p * 8);
                bf16x8 b1 = *(const bf16x8*)(Bs + (wc * 64 + 1 * 16 + l15) * 64 + p * 8);
                bf16x8 b2 = *(const bf16x8*)(Bs + (wc * 64 + 2 * 16 + l15) * 64 + p * 8);
                #pragma unroll
                for (int m = 0; m < 4; ++m) {
                    acc[m][0] = __builtin_amdgcn_mfma_f32_16x16x32_bf16(af[m], b0, acc[m][0], 0, 0, 0);
                    acc[m][1] = __builtin_amdgcn_mfma_f32_16x16x32_bf16(af[m], b1, acc[m][1], 0, 0, 0);
                    acc[m][2] = __builtin_amdgcn_mfma_f32_16x16x32_bf16(af[m], b2, acc[m][2], 0, 0, 0);
                }
            }
        }
    }

    // fused GRU epilogue: acc[m][gate][j]; col = c0*32 + wc*16 + l15
    const int col = c0 * 32 + wc * 16 + l15;
    #pragma unroll
    for (int m = 0; m < 4; ++m)
        #pragma unroll
        for (int j = 0; j < 4; ++j) {
            int i   = m0 + wr * 64 + m * 16 + l4 * 4 + j;     // compacted index
            int rb  = rl_n[i];                                 // batch index
            size_t ridx = (size_t)rb * NRIM + n;
            float reset = fsig(acc[m][0][j]);
            float inp   = fsig(acc[m][1][j]);
            float newg  = ftanh_(acc[m][2][j] + reset * acc[m][3][j]);
            float h     = __bfloat162float(A2[ridx * K2P + col]);
            hyB[ridx * HID + col] = __float2bfloat16(newg + inp * (h - newg));
        }
}

// ---------------- K3 GEMM: qkv[(b*16+n)][1280] = hy @ Wqkv^T (coalesced) -----------
__global__ __launch_bounds__(256)
void k3g(const hbf* __restrict__ hyB, const hbf* __restrict__ Wqkv, hbf* __restrict__ qkv)
{
    __shared__ __align__(16) short As[128 * 64];
    __shared__ __align__(16) short Bs[128 * 64];
    const int id = blockIdx.x;
    const int xcd = id & 7, idx = id >> 3;          // idx in [0,320)
    const int n  = xcd + (idx / 160) * 8;
    const int rem = idx % 160;
    const int m0 = (rem / 10) * 128;                // batch-tile base
    const int c0 = (rem % 10) * 128;

    const hbf* A = hyB + (size_t)n * HID + (size_t)m0 * (NRIM * HID);
    const hbf* B = Wqkv + (size_t)n * (1280 * 256) + (size_t)c0 * 256;

    f32x4 acc[4][4];
    f32x4 zz = {0.0f, 0.0f, 0.0f, 0.0f};
    #pragma unroll
    for (int m = 0; m < 4; ++m)
        #pragma unroll
        for (int nb = 0; nb < 4; ++nb) acc[m][nb] = zz;

    gemm_core64(A, NRIM * HID, B, 256, 256, As, Bs, acc);

    const int t = threadIdx.x;
    const int w = t >> 6, lane = t & 63, l15 = lane & 15, l4 = lane >> 4;
    const int wr = w >> 1, wc = w & 1;
    #pragma unroll
    for (int m = 0; m < 4; ++m)
        #pragma unroll
        for (int nb = 0; nb < 4; ++nb) {
            int col = c0 + wc * 64 + nb * 16 + l15;
            int rb  = m0 + wr * 64 + m * 16 + l4 * 4;   // batch base for this lane
            #pragma unroll
            for (int j = 0; j < 4; ++j)
                qkv[((size_t)(rb + j) * 16 + n) * 1280 + col] = __float2bfloat16(acc[m][nb][j]);
        }
}

// ---------------- K4: attention, MFMA + LDS V-transpose, block per b ---------------
__global__ __launch_bounds__(256)
void k4_attn(const hbf* __restrict__ qkv, const float* __restrict__ maskg,
             hbf* __restrict__ ctx)
{
    const int b = blockIdx.x;
    const int t = threadIdx.x;
    const int w = t >> 6, lane = t & 63;
    const int l15 = lane & 15, g = lane >> 4;

    __shared__ hbf vS[16 * 1024];   // V[m][h*256+d], 32KB

    {
        const int r = t >> 4, c = t & 15;
        const uint4* src = (const uint4*)(qkv + (size_t)(b * 16 + r) * 1280 + 256);
        uint4* dst = (uint4*)(vS + r * 1024);
        #pragma unroll
        for (int i = 0; i < 8; ++i) dst[c + i * 16] = src[c + i * 16];
    }

    // S^T = K @ Q^T : lane holds S[m=4g+j][n=l15]
    const hbf* qrow = qkv + (size_t)(b * 16 + l15) * 1280 + w * 32 + g * 8;
    bf16x8 qf = *(const bf16x8*)(qrow);
    bf16x8 kf = *(const bf16x8*)(qrow + 128);
    f32x4 s = {0.f, 0.f, 0.f, 0.f};
    s = __builtin_amdgcn_mfma_f32_16x16x32_bf16(kf, qf, s, 0, 0, 0);

    const float scale = 0.17677669529663687f;
    float v0 = s[0] * scale, v1 = s[1] * scale, v2 = s[2] * scale, v3 = s[3] * scale;
    float mx = fmaxf(fmaxf(v0, v1), fmaxf(v2, v3));
    mx = fmaxf(mx, __shfl_xor(mx, 16));
    mx = fmaxf(mx, __shfl_xor(mx, 32));
    float e0 = __expf(v0 - mx), e1 = __expf(v1 - mx);
    float e2 = __expf(v2 - mx), e3 = __expf(v3 - mx);
    float sm = e0 + e1 + e2 + e3;
    sm += __shfl_xor(sm, 16);
    sm += __shfl_xor(sm, 32);
    float inv = maskg[b * NRIM + l15] / sm;   // row-mask * softmax-normalize

    unsigned u0 = packbf(e0 * inv, e1 * inv);
    unsigned u1 = packbf(e2 * inv, e3 * inv);
    int sl = l15 + (g << 5);
    unsigned f0 = __shfl((int)u0, sl);
    unsigned f1 = __shfl((int)u1, sl);
    unsigned f2 = __shfl((int)u0, sl + 16);
    unsigned f3 = __shfl((int)u1, sl + 16);
    if (lane >= 32) { f0 = 0; f1 = 0; f2 = 0; f3 = 0; }
    union { unsigned u[4]; bf16x8 v; } pf;
    pf.u[0] = f0; pf.u[1] = f1; pf.u[2] = f2; pf.u[3] = f3;

    __syncthreads();

    const unsigned short* vsu = (const unsigned short*)vS;
    const int vbase = (8 * (g & 1)) * 1024 + w * 256 + l15;
    hbf* crow = ctx + (size_t)(b * 16 + l15) * 1024 + w * 256 + g * 4;
    #pragma unroll
    for (int dc = 0; dc < 16; ++dc) {
        union { unsigned short u[8]; bf16x8 v; } vf;
        #pragma unroll
        for (int e = 0; e < 8; ++e)
            vf.u[e] = vsu[vbase + e * 1024 + dc * 16];
        f32x4 o = {0.f, 0.f, 0.f, 0.f};
        o = __builtin_amdgcn_mfma_f32_16x16x32_bf16(vf.v, pf.v, o, 0, 0, 0);
        unsigned lo = packbf(o[0], o[1]);
        unsigned hi = packbf(o[2], o[3]);
        *(uint2*)(crow + dc * 16) = make_uint2(lo, hi);
    }
}

// ------- K5 GEMM, 64-row tiles: out = mask ? ctx @ Wout^T + hy : hs ----------------
__global__ __launch_bounds__(256)
void k5g(const hbf* __restrict__ ctx, const hbf* __restrict__ Wout,
         const hbf* __restrict__ hyB, const float* __restrict__ hs,
         const float* __restrict__ maskg, float* __restrict__ out)
{
    __shared__ __align__(16) short As[64 * 64];
    __shared__ __align__(16) short Bs[128 * 64];
    const int id = blockIdx.x;                      // 1024 blocks
    const int xcd = id & 7, idx = id >> 3;          // idx in [0,128)
    const int n  = xcd + ((idx >> 6) << 3);
    const int rem = idx & 63;
    const int m0 = (rem >> 1) * 64;                 // batch-tile base (64 rows)
    const int c0 = (rem & 1) * 128;

    const int t = threadIdx.x;
    const int w = t >> 6, lane = t & 63;
    const int l15 = lane & 15, l4 = lane >> 4;
    const int rl = lane >> 3;
    const int gu = (lane & 7) ^ rl;
    const int l7 = l15 & 7;
    const int wr = w >> 1, wc = w & 1;

    const hbf* Bb = Wout + (size_t)n * (256 * 1024) + (size_t)c0 * 1024;

    const hbf* pa[2];
    #pragma unroll
    for (int q = 0; q < 2; ++q) {
        int b = m0 + q * 32 + w * 8 + rl;
        pa[q] = ctx + ((size_t)b * 16 + n) * 1024 + gu * 8;
    }
    const hbf* pb[4];
    #pragma unroll
    for (int q = 0; q < 4; ++q) {
        int row = q * 32 + w * 8 + rl;
        pb[q] = Bb + (size_t)row * 1024 + gu * 8;
    }

    f32x4 acc[2][4];
    f32x4 zz = {0.0f, 0.0f, 0.0f, 0.0f};
    #pragma unroll
    for (int m = 0; m < 2; ++m)
        #pragma unroll
        for (int nb = 0; nb < 4; ++nb) acc[m][nb] = zz;

    for (int kk = 0; kk < 1024; kk += 64) {
        __syncthreads();
        #pragma unroll
        for (int q = 0; q < 2; ++q) {
            GLL(pa[q], As + (q * 32 + w * 8) * 64);
            pa[q] += 64;
        }
        #pragma unroll
        for (int q = 0; q < 4; ++q) {
            GLL(pb[q], Bs + (q * 32 + w * 8) * 64);
            pb[q] += 64;
        }
        __syncthreads();
        #pragma unroll
        for (int ks = 0; ks < 2; ++ks) {
            const int p = (ks * 4 + l4) ^ l7;
            bf16x8 af[2], bfr[4];
            #pragma unroll
            for (int m = 0; m < 2; ++m)
                af[m] = *(const bf16x8*)(As + (wr * 32 + m * 16 + l15) * 64 + p * 8);
            #pragma unroll
            for (int nb = 0; nb < 4; ++nb)
                bfr[nb] = *(const bf16x8*)(Bs + (wc * 64 + nb * 16 + l15) * 64 + p * 8);
            #pragma unroll
            for (int m = 0; m < 2; ++m)
                #pragma unroll
                for (int nb = 0; nb < 4; ++nb)
                    acc[m][nb] = __builtin_amdgcn_mfma_f32_16x16x32_bf16(af[m], bfr[nb], acc[m][nb], 0, 0, 0);
        }
    }

    #pragma unroll
    for (int m = 0; m < 2; ++m)
        #pragma unroll
        for (int j = 0; j < 4; ++j) {
            int row = m0 + wr * 32 + m * 16 + l4 * 4 + j;     // batch index
            float mk = maskg[row * NRIM + n];
            #pragma unroll
            for (int nb = 0; nb < 4; ++nb) {
                int col = c0 + wc * 64 + nb * 16 + l15;
                size_t idx2 = ((size_t)row * NRIM + n) * HID + col;
                out[idx2] = (mk > 0.5f) ? (acc[m][nb][j] + __bfloat162float(hyB[idx2]))
                                        : hs[idx2];
            }
        }
}

extern "C" void kernel_launch(void* const* d_in, const int* in_sizes, int n_in,
                              void* d_out, int out_size, void* d_ws, size_t ws_size,
                              hipStream_t stream) {
    const float* x       = (const float*)d_in[0];
    const float* hs      = (const float*)d_in[1];
    const float* option  = (const float*)d_in[2];
    const float* value_w = (const float*)d_in[3];
    const float* value_b = (const float*)d_in[4];
    const float* p_w     = (const float*)d_in[5];
    const float* p_b     = (const float*)d_in[6];
    const float* x2h_w   = (const float*)d_in[7];
    const float* h2h_w   = (const float*)d_in[8];
    const float* q_w     = (const float*)d_in[9];
    const float* k_w     = (const float*)d_in[10];
    const float* v_w     = (const float*)d_in[11];
    const float* out_w   = (const float*)d_in[12];
    float* out = (float*)d_out;

    char* ws = (char*)d_ws;
    hbf* A2   = (hbf*)(ws);
    hbf* ctx  = (hbf*)(ws);
    size_t off = 67108864;
    hbf* qkv  = (hbf*)(ws + off);
    off += 83886080;
    hbf* W2   = (hbf*)(ws + off); off += 23068672;   // [16][1024][704]
    hbf* Wqkv = (hbf*)(ws + off); off += 10485760;   // [16][1280][256]
    hbf* Wout = (hbf*)(ws + off); off += 8388608;    // [16][256][1024]
    hbf* hyB  = (hbf*)(ws + off); off += 16777216;   // [32768][256]
    float* vl0   = (float*)(ws + off); off += 4194304;   // [2048][512] f32
    hbf* xB   = (hbf*)(ws + off); off += 2097152;    // [2048][512] bf16
    hbf* Wv   = (hbf*)(ws + off); off += 524288;     // [512][512] bf16
    float* p0g   = (float*)(ws + off); off += 131072;
    float* maskg = (float*)(ws + off); off += 131072;
    int* rowcnt  = (int*)(ws + off);   off += 256;
    int* rowlist = (int*)(ws + off);   off += 131072;    // [16][2048]

    mega_prep<<<dim3(20364), dim3(256), 0, stream>>>(
        h2h_w, x2h_w, q_w, k_w, v_w, out_w, value_w, option, p_w, p_b, x,
        W2, Wqkv, Wout, Wv, p0g, maskg, xB);

    k_compact<<<dim3(NRIM), dim3(256), 0, stream>>>(maskg, rowcnt, rowlist);

    k1v<<<dim3(64), dim3(256), 0, stream>>>(xB, Wv, value_b, vl0);
    k1b_a2<<<dim3(BATCH), dim3(256), 0, stream>>>(hs, vl0, p0g, maskg, value_b, A2);

    k2g<<<dim3(2048), dim3(256), 0, stream>>>(A2, W2, rowcnt, rowlist, hyB);

    k3g<<<dim3(2560), dim3(256), 0, stream>>>(hyB, Wqkv, qkv);

    k4_attn<<<dim3(BATCH), dim3(256), 0, stream>>>(qkv, maskg, ctx);

    k5g<<<dim3(1024), dim3(256), 0, stream>>>(ctx, Wout, hyB, hs, maskg, out);
}

// Round 16
// 202.976 us; speedup vs baseline: 1.0423x; 1.0423x over previous
//
#include <hip/hip_runtime.h>
#include <hip/hip_bf16.h>
#include <math.h>

#define BATCH 2048
#define INDIM 512
#define HID   256
#define NRIM  16
#define VAL   400
#define ONUM  8
#define CH    4
#define CK    32
#define CV    256
#define KACT  8
#define K2P   704   // GRU K padded to multiple of 64 (672 -> 704)

typedef __hip_bfloat16 hbf;
typedef __attribute__((ext_vector_type(8))) __bf16 bf16x8;
typedef __attribute__((ext_vector_type(4))) float f32x4;

__device__ __forceinline__ float fsig(float x) {
    x = fminf(fmaxf(x, -30.0f), 30.0f);
    return 1.0f / (1.0f + __expf(-x));
}
__device__ __forceinline__ float ftanh_(float x) {
    x = fminf(fmaxf(x, -15.0f), 15.0f);
    float e = __expf(2.0f * x);
    return (e - 1.0f) / (e + 1.0f);
}

__device__ __forceinline__ unsigned packbf(float a, float b) {
    hbf ha = __float2bfloat16(a), hb = __float2bfloat16(b);
    unsigned short ua, ub;
    __builtin_memcpy(&ua, &ha, 2);
    __builtin_memcpy(&ub, &hb, 2);
    return ((unsigned)ub << 16) | ua;
}

#define GLL(g, l) __builtin_amdgcn_global_load_lds(                                   \
    (const __attribute__((address_space(1))) void*)(g),                               \
    (__attribute__((address_space(3))) void*)(l), 16, 0, 0)

// ------- transpose+convert (vectorized): dst[n][coff+cmap(c)][koff+k] = src[n][k][c]
// One float4 load / thread, one packed uint2 (4x bf16) store / thread.
// k-overshoot rows (k>=K) store zeros — benign overlap with the Z1 zero region.
__device__ __forceinline__ void t_conv_body(
    const float* __restrict__ src, hbf* __restrict__ dst,
    int K, int C, long s_ns, long d_ns, int dstride,
    int koff, int coff, int cmode, int bx, int by, int bz, float* tileS)
{
    const int c0 = bx * 32, k0 = by * 32;
    const int t = threadIdx.x;
    float (*tile)[33] = (float(*)[33])tileS;
    const float* s = src + (size_t)bz * s_ns;

    // load: thread (kr = t>>3, cg = t&7) loads float4 src[k0+kr][c0+cg*4 ..+3]
    {
        const int kr = t >> 3, cg = t & 7;
        const int k = k0 + kr, c = c0 + cg * 4;
        float4 v;
        if (k < K && c + 3 < C) {
            v = *(const float4*)(s + (size_t)k * C + c);
        } else {
            v.x = (k < K && c + 0 < C) ? s[(size_t)k * C + c + 0] : 0.0f;
            v.y = (k < K && c + 1 < C) ? s[(size_t)k * C + c + 1] : 0.0f;
            v.z = (k < K && c + 2 < C) ? s[(size_t)k * C + c + 2] : 0.0f;
            v.w = (k < K && c + 3 < C) ? s[(size_t)k * C + c + 3] : 0.0f;
        }
        tile[kr][cg * 4 + 0] = v.x;
        tile[kr][cg * 4 + 1] = v.y;
        tile[kr][cg * 4 + 2] = v.z;
        tile[kr][cg * 4 + 3] = v.w;
    }
    __syncthreads();
    // store: thread (cr = t>>3, kg = t&7) writes 4 bf16 (one uint2) of dest row cr
    {
        const int cr = t >> 3, kg = t & 7;
        const int c = c0 + cr;
        if (c < C) {
            const int cc = coff + (cmode ? (c < 512 ? c : c + 256) : c);
            hbf* drow = dst + (size_t)bz * d_ns + (size_t)cc * dstride + koff + k0 + kg * 4;
            float v0 = tile[kg * 4 + 0][cr];
            float v1 = tile[kg * 4 + 1][cr];
            float v2 = tile[kg * 4 + 2][cr];
            float v3 = tile[kg * 4 + 3][cr];
            *(uint2*)drow = make_uint2(packbf(v0, v1), packbf(v2, v3));
        }
    }
}

// ---------------- mega_prep: all weight transposes + targeted zeros + k1s + k_xb ---
__global__ __launch_bounds__(256)
void mega_prep(const float* __restrict__ h2h_w, const float* __restrict__ x2h_w,
               const float* __restrict__ q_w, const float* __restrict__ k_w,
               const float* __restrict__ v_w, const float* __restrict__ out_w,
               const float* __restrict__ value_w, const float* __restrict__ option,
               const float* __restrict__ p_w, const float* __restrict__ p_b,
               const float* __restrict__ x,
               hbf* __restrict__ W2, hbf* __restrict__ Wqkv, hbf* __restrict__ Wout,
               hbf* __restrict__ Wv, float* __restrict__ p0g, float* __restrict__ maskg,
               hbf* __restrict__ xB)
{
    __shared__ float tileS[32 * 33];
    const int id = blockIdx.x;
    const int t  = threadIdx.x;

    if (id < 3072) {
        int l = id, bz = l / 192, rem = l % 192;
        t_conv_body(h2h_w, W2, 256, 768, 196608L, 720896L, K2P, 0, 0, 1,
                    rem % 24, rem / 24, bz, tileS);
    } else if (id < 8064) {
        int l = id - 3072, bz = l / 312, rem = l % 312;
        t_conv_body(x2h_w, W2, 400, 768, 307200L, 720896L, K2P, 256, 0, 0,
                    rem % 24, rem / 24, bz, tileS);
    } else if (id < 8576) {
        int l = id - 8064, bz = l / 32, rem = l % 32;
        t_conv_body(q_w, Wqkv, 256, 128, 32768L, 327680L, 256, 0, 0, 0,
                    rem % 4, rem / 4, bz, tileS);
    } else if (id < 9088) {
        int l = id - 8576, bz = l / 32, rem = l % 32;
        t_conv_body(k_w, Wqkv, 256, 128, 32768L, 327680L, 256, 0, 128, 0,
                    rem % 4, rem / 4, bz, tileS);
    } else if (id < 13184) {
        int l = id - 9088, bz = l / 256, rem = l % 256;
        t_conv_body(v_w, Wqkv, 256, 1024, 262144L, 327680L, 256, 0, 256, 0,
                    rem % 32, rem / 32, bz, tileS);
    } else if (id < 17280) {
        int l = id - 13184, bz = l / 256, rem = l % 256;
        t_conv_body(out_w, Wout, 1024, 256, 262144L, 262144L, 1024, 0, 0, 0,
                    rem % 8, rem / 8, bz, tileS);
    } else if (id < 17488) {
        int l = id - 17280;
        t_conv_body(value_w, Wv, 512, 400, 0L, 0L, 512, 0, 0, 0,
                    l % 13, l / 13, 0, tileS);
    } else if (id < 18672) {
        int l = id - 17488, n = l / 74, idx = (l % 74) * 256 + t;
        uint4 z; z.x = 0; z.y = 0; z.z = 0; z.w = 0;
        uint4* base = (uint4*)(W2 + (size_t)n * 720896);
        if (idx < 14336) {
            int c = 768 + idx / 56, u = 32 + idx % 56;
            base[(size_t)c * 88 + u] = z;
        } else {
            int i2 = idx - 14336;
            int c = i2 / 6, u = 82 + i2 % 6;
            base[(size_t)c * 88 + u] = z;
        }
    } else if (id < 18700) {
        int idx = (id - 18672) * 256 + t;
        int c = 400 + idx / 64, u = idx % 64;
        uint4 z; z.x = 0; z.y = 0; z.z = 0; z.w = 0;
        ((uint4*)Wv)[(size_t)c * 64 + u] = z;
    } else if (id < 19212) {
        int l = id - 18700, n = l / 32, idx = (l % 32) * 256 + t;
        int c = 512 + idx / 32, u = idx % 32;
        uint4 z; z.x = 0; z.y = 0; z.z = 0; z.w = 0;
        ((uint4*)(W2 + (size_t)n * 720896))[(size_t)c * 88 + u] = z;
    } else if (id < 19340) {
        const int bb = t >> 4, n = t & 15;
        const int b  = (id - 19212) * 16 + bb;
        float (*sc)[17] = (float(*)[17])tileS;
        float s0 = p_b[n], s1 = 0.0f;
        #pragma unroll
        for (int o = 0; o < ONUM; ++o) {
            s0 = fmaf(option[(b * 2 + 0) * ONUM + o], p_w[o * NRIM + n], s0);
            s1 = fmaf(option[(b * 2 + 1) * ONUM + o], p_w[o * NRIM + n], s1);
        }
        sc[bb][n] = s0;
        __syncthreads();
        int rank = 0;
        #pragma unroll
        for (int m = 0; m < NRIM; ++m) {
            float sm = sc[bb][m];
            if (sm > s0 || (sm == s0 && m < n)) rank++;
        }
        float mk = (rank < KACT) ? 1.0f : 0.0f;
        float mx = fmaxf(s0, s1);
        float e0 = __expf(s0 - mx), e1 = __expf(s1 - mx);
        p0g[b * NRIM + n]   = e0 / (e0 + e1);
        maskg[b * NRIM + n] = mk;
    } else {
        int i = (id - 19340) * 256 + t;
        float4 v = ((const float4*)x)[i];
        unsigned lo = packbf(v.x, v.y), hi = packbf(v.z, v.w);
        *(uint2*)(xB + (size_t)i * 4) = make_uint2(lo, hi);
    }
}

// ---------------- K1b: A2 assembly, flat-parallel ----------------------------------
__global__ __launch_bounds__(256)
void k1b_a2(const float* __restrict__ hs, const float* __restrict__ vl0,
            const float* __restrict__ p0g, const float* __restrict__ maskg,
            const float* __restrict__ value_b, hbf* __restrict__ A2)
{
    const int b = blockIdx.x;
    const int t = threadIdx.x;
    __shared__ float vS[VAL], bS[VAL];
    __shared__ float p0S[16], mkS[16];
    if (t < 100) {
        ((float4*)vS)[t] = ((const float4*)(vl0 + (size_t)b * 512))[t];
        ((float4*)bS)[t] = ((const float4*)value_b)[t];
    }
    if (t >= 224 && t < 240) p0S[t - 224] = p0g[b * NRIM + (t - 224)];
    if (t >= 240)            mkS[t - 240] = maskg[b * NRIM + (t - 240)];
    __syncthreads();

    const size_t base = (size_t)b * NRIM;

    // hs part: 16 rows x 64 float4 -> uint2 ; 1024 tasks, 4 coalesced iters
    #pragma unroll
    for (int it = 0; it < 4; ++it) {
        int idx = it * 256 + t;
        int n = idx >> 6, j = idx & 63;
        float4 hv = ((const float4*)(hs + (base + n) * HID))[j];
        uint2 o = make_uint2(packbf(hv.x, hv.y), packbf(hv.z, hv.w));
        *(uint2*)(A2 + (base + n) * K2P + j * 4) = o;
    }

    // masked-input part: 16 rows x 100 float4 (from LDS) -> uint2 ; 1600 tasks
    for (int idx = t; idx < 1600; idx += 256) {
        int n = idx / 100, j = idx - n * 100;
        float p0 = p0S[n], mk = mkS[n];
        float4 v  = ((const float4*)vS)[j];
        float4 bb = ((const float4*)bS)[j];
        float a0 = mk * (p0 * v.x + (1.0f - p0) * bb.x);
        float a1 = mk * (p0 * v.y + (1.0f - p0) * bb.y);
        float a2 = mk * (p0 * v.z + (1.0f - p0) * bb.z);
        float a3 = mk * (p0 * v.w + (1.0f - p0) * bb.w);
        uint2 o = make_uint2(packbf(a0, a1), packbf(a2, a3));
        *(uint2*)(A2 + (base + n) * K2P + 256 + j * 4) = o;
    }

    // pad part: 16 rows x 48 bf16 zeros = 96 uint4 tasks
    if (t < 96) {
        int n = t / 6, j = t - n * 6;
        uint4 z; z.x = 0; z.y = 0; z.z = 0; z.w = 0;
        *(uint4*)(A2 + (base + n) * K2P + 656 + j * 8) = z;
    }
}

// ------ MFMA GEMM core: BK=64, swizzled LDS, loop-carried pointers -----------------
__device__ __forceinline__ void gemm_core64(const hbf* __restrict__ A, long lda,
                                            const hbf* __restrict__ B, long ldb,
                                            int K, short* As, short* Bs, f32x4 acc[4][4])
{
    const int t = threadIdx.x;
    const int w = t >> 6, lane = t & 63;
    const int l15 = lane & 15, l4 = lane >> 4;
    const int rl = lane >> 3;
    const int gu = (lane & 7) ^ rl;
    const int l7 = l15 & 7;

    const hbf* pa[4];
    const hbf* pb[4];
    #pragma unroll
    for (int q = 0; q < 4; ++q) {
        int row = q * 32 + w * 8 + rl;
        pa[q] = A + (size_t)row * lda + gu * 8;
        pb[q] = B + (size_t)row * ldb + gu * 8;
    }

    for (int kk = 0; kk < K; kk += 64) {
        __syncthreads();
        #pragma unroll
        for (int q = 0; q < 4; ++q) {
            GLL(pa[q], As + (q * 32 + w * 8) * 64);
            GLL(pb[q], Bs + (q * 32 + w * 8) * 64);
            pa[q] += 64; pb[q] += 64;
        }
        __syncthreads();

        const int wr = w >> 1, wc = w & 1;
        #pragma unroll
        for (int ks = 0; ks < 2; ++ks) {
            const int p = (ks * 4 + l4) ^ l7;
            bf16x8 af[4], bfr[4];
            #pragma unroll
            for (int m = 0; m < 4; ++m)
                af[m] = *(const bf16x8*)(As + (wr * 64 + m * 16 + l15) * 64 + p * 8);
            #pragma unroll
            for (int nb = 0; nb < 4; ++nb)
                bfr[nb] = *(const bf16x8*)(Bs + (wc * 64 + nb * 16 + l15) * 64 + p * 8);
            #pragma unroll
            for (int m = 0; m < 4; ++m)
                #pragma unroll
                for (int nb = 0; nb < 4; ++nb)
                    acc[m][nb] = __builtin_amdgcn_mfma_f32_16x16x32_bf16(af[m], bfr[nb], acc[m][nb], 0, 0, 0);
        }
    }
}

// ---------------- K1v GEMM: vl0[2048][512] = xB @ Wv^T + value_b -------------------
__global__ __launch_bounds__(256)
void k1v(const hbf* __restrict__ xB, const hbf* __restrict__ Wv,
         const float* __restrict__ value_b, float* __restrict__ vl0)
{
    __shared__ __align__(16) short As[128 * 64];
    __shared__ __align__(16) short Bs[128 * 64];
    const int m0 = (blockIdx.x >> 2) * 128;
    const int c0 = (blockIdx.x & 3) * 128;

    const hbf* A = xB + (size_t)m0 * INDIM;
    const hbf* B = Wv + (size_t)c0 * INDIM;

    f32x4 acc[4][4];
    f32x4 zz = {0.0f, 0.0f, 0.0f, 0.0f};
    #pragma unroll
    for (int m = 0; m < 4; ++m)
        #pragma unroll
        for (int nb = 0; nb < 4; ++nb) acc[m][nb] = zz;

    gemm_core64(A, INDIM, B, INDIM, INDIM, As, Bs, acc);

    const int t = threadIdx.x;
    const int w = t >> 6, lane = t & 63, l15 = lane & 15, l4 = lane >> 4;
    const int wr = w >> 1, wc = w & 1;
    #pragma unroll
    for (int nb = 0; nb < 4; ++nb) {
        int col = c0 + wc * 64 + nb * 16 + l15;
        float bias = (col < VAL) ? value_b[col] : 0.0f;
        #pragma unroll
        for (int m = 0; m < 4; ++m)
            #pragma unroll
            for (int j = 0; j < 4; ++j) {
                int row = m0 + wr * 64 + m * 16 + l4 * 4 + j;
                vl0[(size_t)row * 512 + col] = acc[m][nb][j] + bias;
            }
    }
}

// ------ K2 GEMM + fused GRU, gate-aware K-range skipping ---------------------------
__global__ __launch_bounds__(256)
void k2g(const hbf* __restrict__ A2, const hbf* __restrict__ W2, hbf* __restrict__ hyB)
{
    __shared__ __align__(16) short As[128 * 64];
    __shared__ __align__(16) short Bs[128 * 64];
    const int id = blockIdx.x;
    const int xcd = id & 7, idx = id >> 3;
    const int n  = xcd + ((idx >> 7) << 3);
    const int rem = idx & 127;
    const int m0 = (rem >> 3) * 128;       // batch-tile base
    const int c0 = rem & 7;                // hidden-col strip [0,8)

    const hbf* A = A2 + (size_t)n * K2P + (size_t)m0 * (NRIM * K2P);
    const hbf* Bb = W2 + (size_t)n * (1024 * K2P);

    const int t = threadIdx.x;
    const int w = t >> 6, lane = t & 63;
    const int l15 = lane & 15, l4 = lane >> 4;
    const int rl = lane >> 3;
    const int gu = (lane & 7) ^ rl;
    const int l7 = l15 & 7;
    const int wr = w >> 1, wc = w & 1;

    f32x4 acc[4][4];
    f32x4 zz = {0.0f, 0.0f, 0.0f, 0.0f};
    #pragma unroll
    for (int m = 0; m < 4; ++m)
        #pragma unroll
        for (int nb = 0; nb < 4; ++nb) acc[m][nb] = zz;

    const hbf* pa[4];
    const hbf* pb[4];
    int gq[4];
    #pragma unroll
    for (int q = 0; q < 4; ++q) {
        int row = q * 32 + w * 8 + rl;
        int wrow = ((row >> 4) & 3) * 256 + c0 * 32 + ((row >> 6) << 4) + (row & 15);
        pa[q] = A + (size_t)row * (NRIM * K2P) + gu * 8;
        pb[q] = Bb + (size_t)wrow * K2P + gu * 8;
        gq[q] = (2 * q + (w >> 1)) & 3;    // wave-uniform gate of this staging group
    }

    // ---- phase 1: K [0,256), gates {0,1,3} ----
    for (int kk = 0; kk < 256; kk += 64) {
        __syncthreads();
        #pragma unroll
        for (int q = 0; q < 4; ++q) {
            GLL(pa[q], As + (q * 32 + w * 8) * 64);
            if (gq[q] != 2) GLL(pb[q], Bs + (q * 32 + w * 8) * 64);
            pa[q] += 64; pb[q] += 64;
        }
        __syncthreads();
        #pragma unroll
        for (int ks = 0; ks < 2; ++ks) {
            const int p = (ks * 4 + l4) ^ l7;
            bf16x8 af[4];
            #pragma unroll
            for (int m = 0; m < 4; ++m)
                af[m] = *(const bf16x8*)(As + (wr * 64 + m * 16 + l15) * 64 + p * 8);
            bf16x8 b0 = *(const bf16x8*)(Bs + (wc * 64 + 0 * 16 + l15) * 64 + p * 8);
            bf16x8 b1 = *(const bf16x8*)(Bs + (wc * 64 + 1 * 16 + l15) * 64 + p * 8);
            bf16x8 b3 = *(const bf16x8*)(Bs + (wc * 64 + 3 * 16 + l15) * 64 + p * 8);
            #pragma unroll
            for (int m = 0; m < 4; ++m) {
                acc[m][0] = __builtin_amdgcn_mfma_f32_16x16x32_bf16(af[m], b0, acc[m][0], 0, 0, 0);
                acc[m][1] = __builtin_amdgcn_mfma_f32_16x16x32_bf16(af[m], b1, acc[m][1], 0, 0, 0);
                acc[m][3] = __builtin_amdgcn_mfma_f32_16x16x32_bf16(af[m], b3, acc[m][3], 0, 0, 0);
            }
        }
    }

    // ---- phase 2: K [256,704), gates {0,1,2} ----
    for (int kk = 256; kk < K2P; kk += 64) {
        __syncthreads();
        #pragma unroll
        for (int q = 0; q < 4; ++q) {
            GLL(pa[q], As + (q * 32 + w * 8) * 64);
            if (gq[q] != 3) GLL(pb[q], Bs + (q * 32 + w * 8) * 64);
            pa[q] += 64; pb[q] += 64;
        }
        __syncthreads();
        #pragma unroll
        for (int ks = 0; ks < 2; ++ks) {
            const int p = (ks * 4 + l4) ^ l7;
            bf16x8 af[4];
            #pragma unroll
            for (int m = 0; m < 4; ++m)
                af[m] = *(const bf16x8*)(As + (wr * 64 + m * 16 + l15) * 64 + p * 8);
            bf16x8 b0 = *(const bf16x8*)(Bs + (wc * 64 + 0 * 16 + l15) * 64 + p * 8);
            bf16x8 b1 = *(const bf16x8*)(Bs + (wc * 64 + 1 * 16 + l15) * 64 + p * 8);
            bf16x8 b2 = *(const bf16x8*)(Bs + (wc * 64 + 2 * 16 + l15) * 64 + p * 8);
            #pragma unroll
            for (int m = 0; m < 4; ++m) {
                acc[m][0] = __builtin_amdgcn_mfma_f32_16x16x32_bf16(af[m], b0, acc[m][0], 0, 0, 0);
                acc[m][1] = __builtin_amdgcn_mfma_f32_16x16x32_bf16(af[m], b1, acc[m][1], 0, 0, 0);
                acc[m][2] = __builtin_amdgcn_mfma_f32_16x16x32_bf16(af[m], b2, acc[m][2], 0, 0, 0);
            }
        }
    }

    // fused GRU epilogue: acc[m][gate][j]; col = c0*32 + wc*16 + l15
    const int col = c0 * 32 + wc * 16 + l15;
    #pragma unroll
    for (int m = 0; m < 4; ++m)
        #pragma unroll
        for (int j = 0; j < 4; ++j) {
            int row = m0 + wr * 64 + m * 16 + l4 * 4 + j;     // batch index
            size_t ridx = (size_t)row * NRIM + n;
            float reset = fsig(acc[m][0][j]);
            float inp   = fsig(acc[m][1][j]);
            float newg  = ftanh_(acc[m][2][j] + reset * acc[m][3][j]);
            float h     = __bfloat162float(A2[ridx * K2P + col]);
            hyB[ridx * HID + col] = __float2bfloat16(newg + inp * (h - newg));
        }
}

// ---------------- K3 GEMM: qkv[(b*16+n)][1280] = hy @ Wqkv^T (coalesced) -----------
__global__ __launch_bounds__(256)
void k3g(const hbf* __restrict__ hyB, const hbf* __restrict__ Wqkv, hbf* __restrict__ qkv)
{
    __shared__ __align__(16) short As[128 * 64];
    __shared__ __align__(16) short Bs[128 * 64];
    const int id = blockIdx.x;
    const int xcd = id & 7, idx = id >> 3;          // idx in [0,320)
    const int n  = xcd + (idx / 160) * 8;
    const int rem = idx % 160;
    const int m0 = (rem / 10) * 128;                // batch-tile base
    const int c0 = (rem % 10) * 128;

    const hbf* A = hyB + (size_t)n * HID + (size_t)m0 * (NRIM * HID);
    const hbf* B = Wqkv + (size_t)n * (1280 * 256) + (size_t)c0 * 256;

    f32x4 acc[4][4];
    f32x4 zz = {0.0f, 0.0f, 0.0f, 0.0f};
    #pragma unroll
    for (int m = 0; m < 4; ++m)
        #pragma unroll
        for (int nb = 0; nb < 4; ++nb) acc[m][nb] = zz;

    gemm_core64(A, NRIM * HID, B, 256, 256, As, Bs, acc);

    const int t = threadIdx.x;
    const int w = t >> 6, lane = t & 63, l15 = lane & 15, l4 = lane >> 4;
    const int wr = w >> 1, wc = w & 1;
    #pragma unroll
    for (int m = 0; m < 4; ++m)
        #pragma unroll
        for (int nb = 0; nb < 4; ++nb) {
            int col = c0 + wc * 64 + nb * 16 + l15;
            int rb  = m0 + wr * 64 + m * 16 + l4 * 4;   // batch base for this lane
            #pragma unroll
            for (int j = 0; j < 4; ++j)
                qkv[((size_t)(rb + j) * 16 + n) * 1280 + col] = __float2bfloat16(acc[m][nb][j]);
        }
}

// ---------------- K4: attention, MFMA + LDS V-transpose, block per b ---------------
__global__ __launch_bounds__(256)
void k4_attn(const hbf* __restrict__ qkv, const float* __restrict__ maskg,
             hbf* __restrict__ ctx)
{
    const int b = blockIdx.x;
    const int t = threadIdx.x;
    const int w = t >> 6, lane = t & 63;
    const int l15 = lane & 15, g = lane >> 4;

    __shared__ hbf vS[16 * 1024];   // V[m][h*256+d], 32KB

    // stage V coalesced: thread (r=t>>4, c=t&15) copies 8x16B of row r
    {
        const int r = t >> 4, c = t & 15;
        const uint4* src = (const uint4*)(qkv + (size_t)(b * 16 + r) * 1280 + 256);
        uint4* dst = (uint4*)(vS + r * 1024);
        #pragma unroll
        for (int i = 0; i < 8; ++i) dst[c + i * 16] = src[c + i * 16];
    }

    // S^T = K @ Q^T : lane holds S[m=4g+j][n=l15]
    const hbf* qrow = qkv + (size_t)(b * 16 + l15) * 1280 + w * 32 + g * 8;
    bf16x8 qf = *(const bf16x8*)(qrow);
    bf16x8 kf = *(const bf16x8*)(qrow + 128);
    f32x4 s = {0.f, 0.f, 0.f, 0.f};
    s = __builtin_amdgcn_mfma_f32_16x16x32_bf16(kf, qf, s, 0, 0, 0);

    const float scale = 0.17677669529663687f;
    float v0 = s[0] * scale, v1 = s[1] * scale, v2 = s[2] * scale, v3 = s[3] * scale;
    float mx = fmaxf(fmaxf(v0, v1), fmaxf(v2, v3));
    mx = fmaxf(mx, __shfl_xor(mx, 16));
    mx = fmaxf(mx, __shfl_xor(mx, 32));
    float e0 = __expf(v0 - mx), e1 = __expf(v1 - mx);
    float e2 = __expf(v2 - mx), e3 = __expf(v3 - mx);
    float sm = e0 + e1 + e2 + e3;
    sm += __shfl_xor(sm, 16);
    sm += __shfl_xor(sm, 32);
    float inv = maskg[b * NRIM + l15] / sm;   // row-mask * softmax-normalize

    // P^T regs -> B-fragment for PV mfma (lane n=l15 needs m=8g..8g+7; zero g>=2)
    unsigned u0 = packbf(e0 * inv, e1 * inv);
    unsigned u1 = packbf(e2 * inv, e3 * inv);
    int sl = l15 + (g << 5);
    unsigned f0 = __shfl((int)u0, sl);
    unsigned f1 = __shfl((int)u1, sl);
    unsigned f2 = __shfl((int)u0, sl + 16);
    unsigned f3 = __shfl((int)u1, sl + 16);
    if (lane >= 32) { f0 = 0; f1 = 0; f2 = 0; f3 = 0; }
    union { unsigned u[4]; bf16x8 v; } pf;
    pf.u[0] = f0; pf.u[1] = f1; pf.u[2] = f2; pf.u[3] = f3;

    __syncthreads();

    // PV: A-frag lane (row=l15 -> d_local, g -> m-group) from LDS column reads
    const unsigned short* vsu = (const unsigned short*)vS;
    const int vbase = (8 * (g & 1)) * 1024 + w * 256 + l15;   // + e*1024 + dc*16
    hbf* crow = ctx + (size_t)(b * 16 + l15) * 1024 + w * 256 + g * 4;
    #pragma unroll
    for (int dc = 0; dc < 16; ++dc) {
        union { unsigned short u[8]; bf16x8 v; } vf;
        #pragma unroll
        for (int e = 0; e < 8; ++e)
            vf.u[e] = vsu[vbase + e * 1024 + dc * 16];
        f32x4 o = {0.f, 0.f, 0.f, 0.f};
        o = __builtin_amdgcn_mfma_f32_16x16x32_bf16(vf.v, pf.v, o, 0, 0, 0);
        unsigned lo = packbf(o[0], o[1]);
        unsigned hi = packbf(o[2], o[3]);
        *(uint2*)(crow + dc * 16) = make_uint2(lo, hi);
    }
}

// ------- K5 GEMM, 64-row tiles: out = mask ? ctx @ Wout^T + hy : hs ----------------
__global__ __launch_bounds__(256)
void k5g(const hbf* __restrict__ ctx, const hbf* __restrict__ Wout,
         const hbf* __restrict__ hyB, const float* __restrict__ hs,
         const float* __restrict__ maskg, float* __restrict__ out)
{
    __shared__ __align__(16) short As[64 * 64];
    __shared__ __align__(16) short Bs[128 * 64];
    const int id = blockIdx.x;                      // 1024 blocks
    const int xcd = id & 7, idx = id >> 3;          // idx in [0,128)
    const int n  = xcd + ((idx >> 6) << 3);
    const int rem = idx & 63;
    const int m0 = (rem >> 1) * 64;                 // batch-tile base (64 rows)
    const int c0 = (rem & 1) * 128;

    const int t = threadIdx.x;
    const int w = t >> 6, lane = t & 63;
    const int l15 = lane & 15, l4 = lane >> 4;
    const int rl = lane >> 3;
    const int gu = (lane & 7) ^ rl;
    const int l7 = l15 & 7;
    const int wr = w >> 1, wc = w & 1;

    const hbf* Bb = Wout + (size_t)n * (256 * 1024) + (size_t)c0 * 1024;

    const hbf* pa[2];
    #pragma unroll
    for (int q = 0; q < 2; ++q) {
        int b = m0 + q * 32 + w * 8 + rl;
        pa[q] = ctx + ((size_t)b * 16 + n) * 1024 + gu * 8;
    }
    const hbf* pb[4];
    #pragma unroll
    for (int q = 0; q < 4; ++q) {
        int row = q * 32 + w * 8 + rl;
        pb[q] = Bb + (size_t)row * 1024 + gu * 8;
    }

    f32x4 acc[2][4];
    f32x4 zz = {0.0f, 0.0f, 0.0f, 0.0f};
    #pragma unroll
    for (int m = 0; m < 2; ++m)
        #pragma unroll
        for (int nb = 0; nb < 4; ++nb) acc[m][nb] = zz;

    for (int kk = 0; kk < 1024; kk += 64) {
        __syncthreads();
        #pragma unroll
        for (int q = 0; q < 2; ++q) {
            GLL(pa[q], As + (q * 32 + w * 8) * 64);
            pa[q] += 64;
        }
        #pragma unroll
        for (int q = 0; q < 4; ++q) {
            GLL(pb[q], Bs + (q * 32 + w * 8) * 64);
            pb[q] += 64;
        }
        __syncthreads();
        #pragma unroll
        for (int ks = 0; ks < 2; ++ks) {
            const int p = (ks * 4 + l4) ^ l7;
            bf16x8 af[2], bfr[4];
            #pragma unroll
            for (int m = 0; m < 2; ++m)
                af[m] = *(const bf16x8*)(As + (wr * 32 + m * 16 + l15) * 64 + p * 8);
            #pragma unroll
            for (int nb = 0; nb < 4; ++nb)
                bfr[nb] = *(const bf16x8*)(Bs + (wc * 64 + nb * 16 + l15) * 64 + p * 8);
            #pragma unroll
            for (int m = 0; m < 2; ++m)
                #pragma unroll
                for (int nb = 0; nb < 4; ++nb)
                    acc[m][nb] = __builtin_amdgcn_mfma_f32_16x16x32_bf16(af[m], bfr[nb], acc[m][nb], 0, 0, 0);
        }
    }

    // epilogue: mask/residual select
    #pragma unroll
    for (int m = 0; m < 2; ++m)
        #pragma unroll
        for (int j = 0; j < 4; ++j) {
            int row = m0 + wr * 32 + m * 16 + l4 * 4 + j;     // batch index
            float mk = maskg[row * NRIM + n];
            #pragma unroll
            for (int nb = 0; nb < 4; ++nb) {
                int col = c0 + wc * 64 + nb * 16 + l15;
                size_t idx2 = ((size_t)row * NRIM + n) * HID + col;
                out[idx2] = (mk > 0.5f) ? (acc[m][nb][j] + __bfloat162float(hyB[idx2]))
                                        : hs[idx2];
            }
        }
}

extern "C" void kernel_launch(void* const* d_in, const int* in_sizes, int n_in,
                              void* d_out, int out_size, void* d_ws, size_t ws_size,
                              hipStream_t stream) {
    const float* x       = (const float*)d_in[0];
    const float* hs      = (const float*)d_in[1];
    const float* option  = (const float*)d_in[2];
    const float* value_w = (const float*)d_in[3];
    const float* value_b = (const float*)d_in[4];
    const float* p_w     = (const float*)d_in[5];
    const float* p_b     = (const float*)d_in[6];
    const float* x2h_w   = (const float*)d_in[7];
    const float* h2h_w   = (const float*)d_in[8];
    const float* q_w     = (const float*)d_in[9];
    const float* k_w     = (const float*)d_in[10];
    const float* v_w     = (const float*)d_in[11];
    const float* out_w   = (const float*)d_in[12];
    float* out = (float*)d_out;

    char* ws = (char*)d_ws;
    hbf* A2   = (hbf*)(ws);
    hbf* ctx  = (hbf*)(ws);
    size_t off = 67108864;
    hbf* qkv  = (hbf*)(ws + off);
    off += 83886080;
    hbf* W2   = (hbf*)(ws + off); off += 23068672;   // [16][1024][704]
    hbf* Wqkv = (hbf*)(ws + off); off += 10485760;   // [16][1280][256]
    hbf* Wout = (hbf*)(ws + off); off += 8388608;    // [16][256][1024]
    hbf* hyB  = (hbf*)(ws + off); off += 16777216;   // [32768][256]
    float* vl0   = (float*)(ws + off); off += 4194304;   // [2048][512] f32
    hbf* xB   = (hbf*)(ws + off); off += 2097152;    // [2048][512] bf16
    hbf* Wv   = (hbf*)(ws + off); off += 524288;     // [512][512] bf16
    float* p0g   = (float*)(ws + off); off += 131072;
    float* maskg = (float*)(ws + off); off += 131072;

    mega_prep<<<dim3(20364), dim3(256), 0, stream>>>(
        h2h_w, x2h_w, q_w, k_w, v_w, out_w, value_w, option, p_w, p_b, x,
        W2, Wqkv, Wout, Wv, p0g, maskg, xB);

    k1v<<<dim3(64), dim3(256), 0, stream>>>(xB, Wv, value_b, vl0);
    k1b_a2<<<dim3(BATCH), dim3(256), 0, stream>>>(hs, vl0, p0g, maskg, value_b, A2);

    k2g<<<dim3(2048), dim3(256), 0, stream>>>(A2, W2, hyB);

    k3g<<<dim3(2560), dim3(256), 0, stream>>>(hyB, Wqkv, qkv);

    k4_attn<<<dim3(BATCH), dim3(256), 0, stream>>>(qkv, maskg, ctx);

    k5g<<<dim3(1024), dim3(256), 0, stream>>>(ctx, Wout, hyB, hs, maskg, out);
}